// Round 1
// baseline (9.914 us; speedup 1.0000x reference)
//
#include <hip/hip_runtime.h>

// Reference output = log_softmax over a size-1 axis = identically 0.0f
// for all finite inputs (score is tanh-bounded dotted with small v, so
// always finite). Output shape (B=256, T=2048, 1) -> 524288 f32 zeros.
// The only required work is writing 2 MiB of zeros to d_out.

__global__ void TemporalAttention_zero_kernel(float4* __restrict__ out, int n4) {
    int i = blockIdx.x * blockDim.x + threadIdx.x;
    if (i < n4) {
        out[i] = make_float4(0.0f, 0.0f, 0.0f, 0.0f);
    }
}

extern "C" void kernel_launch(void* const* d_in, const int* in_sizes, int n_in,
                              void* d_out, int out_size, void* d_ws, size_t ws_size,
                              hipStream_t stream) {
    // out_size = B*T = 524288, divisible by 4 -> float4 stores (16 B/lane).
    int n4 = out_size / 4;
    const int block = 256;
    int grid = (n4 + block - 1) / block;
    TemporalAttention_zero_kernel<<<grid, block, 0, stream>>>(
        reinterpret_cast<float4*>(d_out), n4);

    // Handle any non-multiple-of-4 tail (defensive; not expected here).
    int tail = out_size - n4 * 4;
    if (tail > 0) {
        float* out_f = reinterpret_cast<float*>(d_out) + n4 * 4;
        // tiny single-block cleanup
        hipMemsetAsync(out_f, 0, tail * sizeof(float), stream);
    }
}